// Round 4
// baseline (324.782 us; speedup 1.0000x reference)
//
#include <hip/hip_runtime.h>
#include <hip/hip_cooperative_groups.h>

// AdjGAT: V=20000, D=256, K=16, O=128, H=4.
// Math: attn[h,v] = x[v].(W_h a_h);  out[v] = relu( (1/H)[ sum_h (sum_k c_hk x[nbr_k]).W_h + sum_h b_h ] )
// R13: single COOPERATIVE mega-kernel. Budget analysis (R9/R11/R12): dur 127 =
//   44 fill (harness, fixed) + 3 prep + 10 xsplit + 45 gat + ~25 launch gaps.
//   Gather is throughput-walled (~164MB logical random 512B reads @ ~4-5TB/s
//   L2/L3; occupancy 16->32 waves/CU bought only ~4us in R12), so attack the
//   gaps: fuse all three launches into one kernel with grid.sync() between
//   phases. Phase bodies are VERBATIM the harness-passed R9 kernels (R12's
//   512-thread reshape caused an unexplained post-timing divergence; retreat
//   to proven 256-thread/4-wave phase code only).
// Loop-carried LDS safety in phase C (tile-strided R9 gat body): the barrier
//   after P1(t+1) orders every wave past P3(t) before any P2(t+1) yl write;
//   the barrier after P2(t) orders all coefs_s reads before P1(t+1) writes.
// Grid: occupancy-query x CU count (expect 4 x 256 = 1024; LDS 38400 -> 4/CU,
//   launch_bounds(256,4) -> VGPR<=128). All phases grid-stride -> any grid ok.
// ws: attn4 0.32MB | xh 10.24MB | Wt 0.26MB | wt 4KB (~10.8MB)

#define V_N 20000
#define D_N 256
#define K_N 16
#define O_N 128
#define H_N 4
#define NEG_INF -1e9f
#define TM 16            // nodes per tile; V = 1250 * 16

typedef _Float16 f16x8 __attribute__((ext_vector_type(8)));
typedef _Float16 f16x4 __attribute__((ext_vector_type(4)));
typedef float    f32x4 __attribute__((ext_vector_type(4)));

namespace cg = cooperative_groups;

__global__ __launch_bounds__(256, 4) void fused_kernel(
    const float* __restrict__ x, const float* __restrict__ W,
    const float* __restrict__ a, const float* __restrict__ b,
    const int* __restrict__ adj, const int* __restrict__ mask_p,
    float* __restrict__ out,
    float* __restrict__ attn4, _Float16* __restrict__ xh,
    _Float16* __restrict__ Wt, float* __restrict__ wt)
{
    cg::grid_group grid = cg::this_grid();
    const int tid  = threadIdx.x;
    const int wid  = tid >> 6;
    const int lane = tid & 63;

    __shared__ int      sidx_s[TM][17];          // +1 pad
    __shared__ float    coefs_s[K_N][17][H_N];   // [k][node(+pad)][h]
    // yl slot (f16x8 units): h*512 + n*32 + (sl ^ n); sl = 16B slot of row
    __shared__ _Float16 yl[H_N * 512 * 8];       // 32KB

    // ======== Phase A: prep (blocks 0-67; verbatim R9 prep_kernel) ========
    if (blockIdx.x < 64) {
        const int idx   = blockIdx.x * 256 + tid;  // 16384 frag-lane slots
        const int plane = idx & 63;
        const int nt    = (idx >> 6) & 7;    // col tile (16 cols)
        const int s     = (idx >> 9) & 7;    // k slice (32 chans)
        const int h     = idx >> 12;
        const int o     = nt * 16 + (plane & 15);
        const int d0    = s * 32 + (plane >> 4) * 8;
        f16x8 v;
        #pragma unroll
        for (int j = 0; j < 8; ++j)
            v[j] = (_Float16)W[((size_t)h * D_N + d0 + j) * O_N + o];
        *(f16x8*)&Wt[(size_t)idx * 8] = v;
    } else if (blockIdx.x < 68) {
        const int h = blockIdx.x - 64;
        const int d = tid;
        const float* Wrow = W + ((size_t)h * D_N + d) * O_N;
        const float* ah   = a + h * O_N;
        float s = 0.f;
        #pragma unroll
        for (int o = 0; o < O_N; o += 4) {
            const float4 wv = *(const float4*)&Wrow[o];
            const float4 av = *(const float4*)&ah[o];
            s = fmaf(wv.x, av.x, s); s = fmaf(wv.y, av.y, s);
            s = fmaf(wv.z, av.z, s); s = fmaf(wv.w, av.w, s);
        }
        wt[h * D_N + d] = s;
    }
    grid.sync();

    // ======== Phase B: xsplit+attn (grid-strided; verbatim R9 body) ========
    {
        const int nwave = gridDim.x * 4;
        for (int v = blockIdx.x * 4 + wid; v < V_N; v += nwave) {
            const float4 p = *(const float4*)&x[(size_t)v * D_N + lane * 4];
            f16x4 hv = { (_Float16)p.x, (_Float16)p.y, (_Float16)p.z, (_Float16)p.w };
            *(f16x4*)&xh[(size_t)v * D_N + lane * 4] = hv;

            float s[H_N];
            #pragma unroll
            for (int h = 0; h < H_N; ++h) {
                const float4 w = *(const float4*)&wt[h * D_N + lane * 4];
                float t = fmaf(p.x, w.x, 0.f);
                t = fmaf(p.y, w.y, t); t = fmaf(p.z, w.z, t); t = fmaf(p.w, w.w, t);
                s[h] = t;
            }
            #pragma unroll
            for (int h = 0; h < H_N; ++h)
                #pragma unroll
                for (int dd = 32; dd >= 1; dd >>= 1)
                    s[h] += __shfl_xor(s[h], dd);
            if (lane == 0)
                *(float4*)&attn4[(size_t)v * 4] = make_float4(s[0], s[1], s[2], s[3]);
        }
    }
    grid.sync();

    // ======== Phase C: gat (tile-strided; verbatim R9 gat_kernel body) ====
    for (int t = blockIdx.x; t < V_N / TM; t += gridDim.x) {
        const int v0 = t * TM;

        // ---- P1: softmax coefs, thread = (node, k) ----
        {
            const int node = tid >> 4;
            const int k    = tid & 15;
            const int mask = mask_p[0];
            const int idx  = adj[(v0 + node) * K_N + k];
            const bool pad = (idx >= mask);
            const int safe = pad ? 0 : idx;
            const float4 av = *(const float4*)&attn4[(size_t)safe * 4];
            const float lg[H_N] = { pad ? NEG_INF : av.x, pad ? NEG_INF : av.y,
                                    pad ? NEG_INF : av.z, pad ? NEG_INF : av.w };
            float c[H_N];
            #pragma unroll
            for (int h = 0; h < H_N; ++h) {
                float m = lg[h];
                #pragma unroll
                for (int s = 8; s >= 1; s >>= 1)
                    m = fmaxf(m, __shfl_xor(m, s, 16));
                const float e = pad ? 0.f : __expf(lg[h] - m);
                float sum = e;
                #pragma unroll
                for (int s = 8; s >= 1; s >>= 1)
                    sum += __shfl_xor(sum, s, 16);
                // pad coef 0 == ref (exp(-1e9-m)==0); all-pad row -> relu(bbar)
                c[h] = pad ? 0.f : e / sum;
            }
            *(float4*)&coefs_s[k][node][0] = make_float4(c[0], c[1], c[2], c[3]);
            sidx_s[node][k] = safe;
        }
        __syncthreads();   // also orders prior-tile P3 yl reads before P2 writes

        // ---- P2: row-gather; wave owns nodes [wid*4, wid*4+4) ----
        {
            const int hw = lane >> 5;         // node parity
            const int sl = lane & 31;         // 16B slot within the 512B row
            const _Float16* xsl = xh + sl * 8;

            float y[2][H_N][8];               // node = wid*4 + 2*i + hw
            #pragma unroll
            for (int i = 0; i < 2; ++i)
                #pragma unroll
                for (int h = 0; h < H_N; ++h)
                    #pragma unroll
                    for (int j = 0; j < 8; ++j) y[i][h][j] = 0.f;

            #pragma unroll 4
            for (int k = 0; k < K_N; ++k) {
                #pragma unroll
                for (int i = 0; i < 2; ++i) {
                    const int n  = wid * 4 + 2 * i + hw;
                    const int si = sidx_s[n][k];
                    const f16x8 xv = *(const f16x8*)&xsl[(size_t)si * D_N];
                    const float4 c = *(const float4*)&coefs_s[k][n][0];
                    const float ch4[H_N] = { c.x, c.y, c.z, c.w };
                    #pragma unroll
                    for (int h = 0; h < H_N; ++h)
                        #pragma unroll
                        for (int j = 0; j < 8; ++j)
                            y[i][h][j] = fmaf(ch4[h], (float)xv[j], y[i][h][j]);
                }
            }
            // fp16 A-fragments, XOR-swizzled (write: contiguous permuted 512B)
            #pragma unroll
            for (int i = 0; i < 2; ++i) {
                const int n    = wid * 4 + 2 * i + hw;
                const int slot = n * 32 + (sl ^ n);
                #pragma unroll
                for (int h = 0; h < H_N; ++h) {
                    f16x8 v;
                    #pragma unroll
                    for (int j = 0; j < 8; ++j) v[j] = (_Float16)y[i][h][j];
                    *(f16x8*)&yl[(size_t)(h * 512 + slot) * 8] = v;
                }
            }
        }
        __syncthreads();

        // ---- P3: col tiles wid*2, wid*2+1 over full K (4h x 8 slices) ----
        const int m = lane & 15;              // node / C col
        const int q = lane >> 4;              // k-group / C row group
        f32x4 acc0 = (f32x4){0.f, 0.f, 0.f, 0.f};
        f32x4 acc1 = (f32x4){0.f, 0.f, 0.f, 0.f};
        {
            const _Float16* Wb = Wt + (size_t)lane * 8;
            #pragma unroll
            for (int h = 0; h < H_N; ++h) {
                #pragma unroll
                for (int s = 0; s < 8; ++s) {
                    const int slot = m * 32 + ((s * 4 + q) ^ m);
                    const f16x8 af = *(const f16x8*)&yl[(size_t)(h * 512 + slot) * 8];
                    const size_t fb = (size_t)((h * 8 + s) * 8 + wid * 2) * 512;
                    const f16x8 b0 = *(const f16x8*)&Wb[fb];
                    const f16x8 b1 = *(const f16x8*)&Wb[fb + 512];
                    acc0 = __builtin_amdgcn_mfma_f32_16x16x32_f16(af, b0, acc0, 0, 0, 0);
                    acc1 = __builtin_amdgcn_mfma_f32_16x16x32_f16(af, b1, acc1, 0, 0, 0);
                }
            }
        }

        // ---- epilogue: mean heads + mean bias + relu; C: col=m, row=q*4+r ----
        #pragma unroll
        for (int nt = 0; nt < 2; ++nt) {
            const f32x4 acc = nt ? acc1 : acc0;
            const int col = (wid * 2 + nt) * 16 + m;
            const float bb = b[col] + b[O_N + col] + b[2 * O_N + col] + b[3 * O_N + col];
            #pragma unroll
            for (int r = 0; r < 4; ++r) {
                const int node = q * 4 + r;
                out[(size_t)(v0 + node) * O_N + col] = fmaxf(0.25f * (acc[r] + bb), 0.f);
            }
        }
        // next-iteration P1's __syncthreads provides the yl-reuse fence
    }
}

extern "C" void kernel_launch(void* const* d_in, const int* in_sizes, int n_in,
                              void* d_out, int out_size, void* d_ws, size_t ws_size,
                              hipStream_t stream) {
    const float* x      = (const float*)d_in[0];
    const float* W      = (const float*)d_in[1];
    const float* a      = (const float*)d_in[2];
    const float* b      = (const float*)d_in[3];
    const int*   adj    = (const int*)d_in[4];
    const int*   mask_p = (const int*)d_in[5];
    float*       out    = (float*)d_out;

    // ws layout (bytes)
    char* p = (char*)d_ws;
    float*    attn4 = (float*)p;                     //    320,000
    _Float16* xh    = (_Float16*)(p + 320000);       // 10,240,000
    _Float16* Wt    = (_Float16*)(p + 10560000);     //    262,144
    float*    wt    = (float*)(p + 10822144);        //      4,096  (~10.8MB)

    // Cooperative grid = co-resident capacity (expect 4 blocks/CU x 256 CU).
    // Computed once; deterministic across calls (harness same-work tripwire).
    static int grid_blocks = 0;
    if (grid_blocks == 0) {
        int per_cu = 0, n_cu = 0;
        hipOccupancyMaxActiveBlocksPerMultiprocessor(&per_cu, fused_kernel, 256, 0);
        hipDeviceGetAttribute(&n_cu, hipDeviceAttributeMultiprocessorCount, 0);
        if (per_cu < 1) per_cu = 4;    // known: LDS 38400 -> 4/CU on MI355X
        if (n_cu   < 1) n_cu   = 256;
        grid_blocks = per_cu * n_cu;
    }

    void* args[] = { (void*)&x, (void*)&W, (void*)&a, (void*)&b,
                     (void*)&adj, (void*)&mask_p, (void*)&out,
                     (void*)&attn4, (void*)&xh, (void*)&Wt, (void*)&wt };
    hipLaunchCooperativeKernel((const void*)fused_kernel,
                               dim3(grid_blocks), dim3(256), args, 0, stream);
}

// Round 6
// 118.323 us; speedup vs baseline: 2.7449x; 2.7449x over previous
//
#include <hip/hip_runtime.h>

// AdjGAT: V=20000, D=256, K=16, O=128, H=4.
// Math: attn[h,v] = x[v].(W_h a_h);  out[v] = relu( (1/H)[ sum_h (sum_k c_hk x[nbr_k]).W_h + sum_h b_h ] )
// R15 == R14 resubmit (R14 bench died in infra: "container failed twice", no
// signal — same transient as R10/R11). R14 change vs proven R9 base:
//   gat P2 accumulates in PACKED FP16 (f16x8 y, v_pk_fma_f16): halves P2 FMA
//   instruction count, deletes 64 cvt before LDS store, frees ~32 VGPR.
//   Precision: fp16 accum over 16 convex terms adds ~0.002 on y -> absmax
//   ~0.004, threshold 0.01125.
// Established: gather wall ~35-45us is TCC request-rate bound (occupancy x2
// bought 4us in R12); fill 44us fixed; gaps ~6us/dispatch; fp8 fails err
// budget; cooperative persistent launch poisons caches (R13: 334us).
// Pipeline (3 launches):
//   KA prep:    blocks 0-63:  W fp32 -> Wt fp16 in EXACT MFMA B-frag order
//               blocks 64-67: wt[h][d] = sum_o W[h][d][o]*a[h][o]
//   KB xsplit:  xh = fp16(x); attn4[v][h] = x[v].wt[h] (fused)
//   KC gat:     16 nodes/block, 256 thr = 4 waves (R6 register structure).
//               P1: softmax coefs (width-16 shuffles).
//               P2: wave owns nodes [wid*4,wid*4+4); each load = 2 contiguous
//                   512B rows; y (2x4 f16x8) packed-fp16 accum -> LDS A-frags
//                   with XOR swizzle (sl^n).
//               P3: wave computes col tiles wid*2, wid*2+1 over full K:
//                   ds_read_b128 A + dense 1KB global B frags + 64 MFMAs.
//               Epilogue: mean heads + mean bias + relu.
// ws: attn4 0.32MB | xh 10.24MB | Wt 0.26MB | wt 4KB  (~10.8MB)

#define V_N 20000
#define D_N 256
#define K_N 16
#define O_N 128
#define H_N 4
#define NEG_INF -1e9f
#define TM 16            // nodes per block; V = 1250 * 16

typedef _Float16 f16x8 __attribute__((ext_vector_type(8)));
typedef _Float16 f16x4 __attribute__((ext_vector_type(4)));
typedef float    f32x4 __attribute__((ext_vector_type(4)));

// ---------------- KA: prep_w (B-frag swizzle) + wtilde, fused ----------------
__global__ __launch_bounds__(256) void prep_kernel(
    const float* __restrict__ W, const float* __restrict__ a,
    _Float16* __restrict__ Wt, float* __restrict__ wt)
{
    if (blockIdx.x < 64) {
        const int idx  = blockIdx.x * 256 + threadIdx.x;  // 16384 frag-lane slots
        const int lane = idx & 63;
        const int nt   = (idx >> 6) & 7;    // col tile (16 cols)
        const int s    = (idx >> 9) & 7;    // k slice (32 chans)
        const int h    = idx >> 12;
        const int o    = nt * 16 + (lane & 15);
        const int d0   = s * 32 + (lane >> 4) * 8;
        f16x8 v;
        #pragma unroll
        for (int j = 0; j < 8; ++j)
            v[j] = (_Float16)W[((size_t)h * D_N + d0 + j) * O_N + o];
        *(f16x8*)&Wt[(size_t)idx * 8] = v;
    } else {
        const int h = blockIdx.x - 64;
        const int d = threadIdx.x;
        const float* Wrow = W + ((size_t)h * D_N + d) * O_N;
        const float* ah   = a + h * O_N;
        float s = 0.f;
        #pragma unroll
        for (int o = 0; o < O_N; o += 4) {
            const float4 wv = *(const float4*)&Wrow[o];
            const float4 av = *(const float4*)&ah[o];
            s = fmaf(wv.x, av.x, s); s = fmaf(wv.y, av.y, s);
            s = fmaf(wv.z, av.z, s); s = fmaf(wv.w, av.w, s);
        }
        wt[h * D_N + d] = s;
    }
}

// ---------------- KB: x -> fp16 copy + fused attn logits ----------------
__global__ __launch_bounds__(256) void xsplit_attn_kernel(
    const float* __restrict__ x, const float* __restrict__ wt,
    _Float16* __restrict__ xh, float* __restrict__ attn4)
{
    const int wid  = threadIdx.x >> 6;
    const int lane = threadIdx.x & 63;
    const int v    = blockIdx.x * 4 + wid;

    const float4 p = *(const float4*)&x[(size_t)v * D_N + lane * 4];
    f16x4 hv = { (_Float16)p.x, (_Float16)p.y, (_Float16)p.z, (_Float16)p.w };
    *(f16x4*)&xh[(size_t)v * D_N + lane * 4] = hv;

    float s[H_N];
    #pragma unroll
    for (int h = 0; h < H_N; ++h) {
        const float4 w = *(const float4*)&wt[h * D_N + lane * 4];
        float t = fmaf(p.x, w.x, 0.f);
        t = fmaf(p.y, w.y, t); t = fmaf(p.z, w.z, t); t = fmaf(p.w, w.w, t);
        s[h] = t;
    }
    #pragma unroll
    for (int h = 0; h < H_N; ++h)
        #pragma unroll
        for (int dd = 32; dd >= 1; dd >>= 1)
            s[h] += __shfl_xor(s[h], dd);
    if (lane == 0)
        *(float4*)&attn4[(size_t)v * 4] = make_float4(s[0], s[1], s[2], s[3]);
}

// ---------------- KC: fused softmax + row-gather + full-K fp16 MFMA ---------
__global__ __launch_bounds__(256, 4) void gat_kernel(
    const _Float16* __restrict__ xh, const float* __restrict__ attn4,
    const _Float16* __restrict__ Wt, const float* __restrict__ b,
    const int* __restrict__ adj, const int* __restrict__ mask_p,
    float* __restrict__ out)
{
    const int v0  = blockIdx.x * TM;
    const int tid = threadIdx.x;

    __shared__ int      sidx_s[TM][17];          // +1 pad
    __shared__ float    coefs_s[K_N][17][H_N];   // [k][node(+pad)][h]
    // yl slot (f16x8 units): h*512 + n*32 + (sl ^ n); sl = s*4 + q' (32B slot of row)
    __shared__ _Float16 yl[H_N * 512 * 8];       // 32KB

    // ---- P1: softmax coefs, thread = (node, k) ----
    {
        const int node = tid >> 4;
        const int k    = tid & 15;
        const int mask = mask_p[0];
        const int idx  = adj[(v0 + node) * K_N + k];
        const bool pad = (idx >= mask);
        const int safe = pad ? 0 : idx;
        const float4 av = *(const float4*)&attn4[(size_t)safe * 4];
        const float lg[H_N] = { pad ? NEG_INF : av.x, pad ? NEG_INF : av.y,
                                pad ? NEG_INF : av.z, pad ? NEG_INF : av.w };
        float c[H_N];
        #pragma unroll
        for (int h = 0; h < H_N; ++h) {
            float m = lg[h];
            #pragma unroll
            for (int s = 8; s >= 1; s >>= 1)
                m = fmaxf(m, __shfl_xor(m, s, 16));
            const float e = pad ? 0.f : __expf(lg[h] - m);
            float sum = e;
            #pragma unroll
            for (int s = 8; s >= 1; s >>= 1)
                sum += __shfl_xor(sum, s, 16);
            // pad coef 0 == ref (exp(-1e9-m)==0); all-pad row -> y=0 -> relu(bbar)
            c[h] = pad ? 0.f : e / sum;
        }
        *(float4*)&coefs_s[k][node][0] = make_float4(c[0], c[1], c[2], c[3]);
        sidx_s[node][k] = safe;
    }
    __syncthreads();

    const int wid  = tid >> 6;
    const int lane = tid & 63;

    // ---- P2: row-gather; wave owns nodes [wid*4, wid*4+4), contiguous rows ----
    // Packed fp16 accumulation: y[i][h] is f16x8, FMAs emit v_pk_fma_f16.
    {
        const int hw = lane >> 5;         // half-wave selects node parity
        const int sl = lane & 31;         // 16B slot within the 512B row
        const _Float16* xsl = xh + sl * 8;

        f16x8 y[2][H_N];                  // node = wid*4 + 2*i + hw
        #pragma unroll
        for (int i = 0; i < 2; ++i)
            #pragma unroll
            for (int h = 0; h < H_N; ++h)
                #pragma unroll
                for (int j = 0; j < 8; ++j) y[i][h][j] = (_Float16)0.f;

        #pragma unroll 4
        for (int k = 0; k < K_N; ++k) {
            #pragma unroll
            for (int i = 0; i < 2; ++i) {
                const int n  = wid * 4 + 2 * i + hw;
                const int si = sidx_s[n][k];
                const f16x8 xv = *(const f16x8*)&xsl[(size_t)si * D_N];
                const float4 c = *(const float4*)&coefs_s[k][n][0];
                const _Float16 c0 = (_Float16)c.x, c1 = (_Float16)c.y,
                               c2 = (_Float16)c.z, c3 = (_Float16)c.w;
                y[i][0] += xv * c0;
                y[i][1] += xv * c1;
                y[i][2] += xv * c2;
                y[i][3] += xv * c3;
            }
        }
        // store fp16 A-fragments, XOR-swizzled (write: contiguous permuted 512B)
        #pragma unroll
        for (int i = 0; i < 2; ++i) {
            const int n    = wid * 4 + 2 * i + hw;
            const int slot = n * 32 + (sl ^ n);
            #pragma unroll
            for (int h = 0; h < H_N; ++h)
                *(f16x8*)&yl[(size_t)(h * 512 + slot) * 8] = y[i][h];
        }
    }
    __syncthreads();

    // ---- P3: col tiles wid*2, wid*2+1 over full K (4h x 8 slices) ----
    const int m = lane & 15;              // node / C col
    const int q = lane >> 4;              // k-group / C row group
    f32x4 acc0 = (f32x4){0.f, 0.f, 0.f, 0.f};
    f32x4 acc1 = (f32x4){0.f, 0.f, 0.f, 0.f};
    {
        const _Float16* Wb = Wt + (size_t)lane * 8;
        #pragma unroll
        for (int h = 0; h < H_N; ++h) {
            #pragma unroll
            for (int s = 0; s < 8; ++s) {
                const int slot = m * 32 + ((s * 4 + q) ^ m);
                const f16x8 af = *(const f16x8*)&yl[(size_t)(h * 512 + slot) * 8];
                const size_t fb = (size_t)((h * 8 + s) * 8 + wid * 2) * 512;
                const f16x8 b0 = *(const f16x8*)&Wb[fb];
                const f16x8 b1 = *(const f16x8*)&Wb[fb + 512];
                acc0 = __builtin_amdgcn_mfma_f32_16x16x32_f16(af, b0, acc0, 0, 0, 0);
                acc1 = __builtin_amdgcn_mfma_f32_16x16x32_f16(af, b1, acc1, 0, 0, 0);
            }
        }
    }

    // ---- epilogue: mean heads + mean bias + relu; C: col=m, row=q*4+r ----
    #pragma unroll
    for (int nt = 0; nt < 2; ++nt) {
        const f32x4 acc = nt ? acc1 : acc0;
        const int col = (wid * 2 + nt) * 16 + m;
        const float bb = b[col] + b[O_N + col] + b[2 * O_N + col] + b[3 * O_N + col];
        #pragma unroll
        for (int r = 0; r < 4; ++r) {
            const int node = q * 4 + r;
            out[(size_t)(v0 + node) * O_N + col] = fmaxf(0.25f * (acc[r] + bb), 0.f);
        }
    }
}

extern "C" void kernel_launch(void* const* d_in, const int* in_sizes, int n_in,
                              void* d_out, int out_size, void* d_ws, size_t ws_size,
                              hipStream_t stream) {
    const float* x      = (const float*)d_in[0];
    const float* W      = (const float*)d_in[1];
    const float* a      = (const float*)d_in[2];
    const float* b      = (const float*)d_in[3];
    const int*   adj    = (const int*)d_in[4];
    const int*   mask_p = (const int*)d_in[5];
    float*       out    = (float*)d_out;

    // ws layout (bytes)
    char* p = (char*)d_ws;
    float*    attn4 = (float*)p;                     //    320,000
    _Float16* xh    = (_Float16*)(p + 320000);       // 10,240,000
    _Float16* Wt    = (_Float16*)(p + 10560000);     //    262,144
    float*    wt    = (float*)(p + 10822144);        //      4,096  (~10.8MB)

    prep_kernel<<<68, 256, 0, stream>>>(W, a, Wt, wt);
    xsplit_attn_kernel<<<V_N / 4, 256, 0, stream>>>(x, wt, xh, attn4);
    gat_kernel<<<V_N / TM, 256, 0, stream>>>(xh, attn4, Wt, b, adj, mask_p, out);
}

// Round 7
// 116.065 us; speedup vs baseline: 2.7983x; 1.0195x over previous
//
#include <hip/hip_runtime.h>

// AdjGAT: V=20000, D=256, K=16, O=128, H=4.
// Math: attn[h,v] = x[v].(W_h a_h);  out[v] = relu( (1/H)[ sum_h (sum_k c_hk x[nbr_k]).W_h + sum_h b_h ] )
// R16 (from R15=118.3us, all kernels < 45us fill):
//  1. Rebalance K1/K2: K1 "prep_all" = Wt frags + wt + xh copy (all mutually
//     independent, one grid); K2 "attn" reads xh (fp16, 10.2MB L3-hot — half
//     the bytes of x) and does only the dot+reduce. Was prep 3 + xsplit 10;
//     now ~6 + ~3. Logits from fp16 xh shift coefs ~3e-4 rel — invisible.
//  2. gat P3: pre-barrier prefetch of first B-frag pair + rotated software
//     pipeline (compiler can't hoist global loads across __syncthreads;
//     pre-barrier issue completes during the barrier drain for free).
// Established: gather wall ~35us TCC-bound; fill 44.6us fixed; gaps ~6us each;
// fp8 gather fails err budget; cooperative launch poisons caches (R13);
// packed-fp16 P2 accum verified (R15, absmax 0.00195 unchanged).
// Pipeline (3 launches):
//   K1 prep_all: blocks 0-63 Wt B-frags | 64-67 wt=W.a | 68+ xh=fp16(x)
//   K2 attn:     attn4[v][h] = xh[v].wt[h]  (dot + width-64 shuffle reduce)
//   K3 gat:      P1 softmax coefs | P2 packed-fp16 gather-aggregate ->
//                XOR-swizzled LDS A-frags | P3 pipelined B-stream + 64 MFMAs
// ws: attn4 0.32MB | xh 10.24MB | Wt 0.26MB | wt 4KB  (~10.8MB)

#define V_N 20000
#define D_N 256
#define K_N 16
#define O_N 128
#define H_N 4
#define NEG_INF -1e9f
#define TM 16            // nodes per block; V = 1250 * 16

typedef _Float16 f16x8 __attribute__((ext_vector_type(8)));
typedef _Float16 f16x4 __attribute__((ext_vector_type(4)));
typedef float    f32x4 __attribute__((ext_vector_type(4)));

// ---------------- K1: Wt B-frag swizzle + wtilde + xh copy (independent) ----
__global__ __launch_bounds__(256) void prep_all_kernel(
    const float* __restrict__ W, const float* __restrict__ a,
    const float* __restrict__ x,
    _Float16* __restrict__ Wt, float* __restrict__ wt,
    _Float16* __restrict__ xh)
{
    if (blockIdx.x >= 68) {
        // xh copy: wave = one 1KB row; lane = float4 (16B) chunk
        const int wid  = threadIdx.x >> 6;
        const int lane = threadIdx.x & 63;
        const int v    = (blockIdx.x - 68) * 4 + wid;
        const float4 p = *(const float4*)&x[(size_t)v * D_N + lane * 4];
        f16x4 hv = { (_Float16)p.x, (_Float16)p.y, (_Float16)p.z, (_Float16)p.w };
        *(f16x4*)&xh[(size_t)v * D_N + lane * 4] = hv;
    } else if (blockIdx.x < 64) {
        const int idx  = blockIdx.x * 256 + threadIdx.x;  // 16384 frag-lane slots
        const int lane = idx & 63;
        const int nt   = (idx >> 6) & 7;    // col tile (16 cols)
        const int s    = (idx >> 9) & 7;    // k slice (32 chans)
        const int h    = idx >> 12;
        const int o    = nt * 16 + (lane & 15);
        const int d0   = s * 32 + (lane >> 4) * 8;
        f16x8 v;
        #pragma unroll
        for (int j = 0; j < 8; ++j)
            v[j] = (_Float16)W[((size_t)h * D_N + d0 + j) * O_N + o];
        *(f16x8*)&Wt[(size_t)idx * 8] = v;
    } else {
        const int h = blockIdx.x - 64;
        const int d = threadIdx.x;
        const float* Wrow = W + ((size_t)h * D_N + d) * O_N;
        const float* ah   = a + h * O_N;
        float s = 0.f;
        #pragma unroll
        for (int o = 0; o < O_N; o += 4) {
            const float4 wv = *(const float4*)&Wrow[o];
            const float4 av = *(const float4*)&ah[o];
            s = fmaf(wv.x, av.x, s); s = fmaf(wv.y, av.y, s);
            s = fmaf(wv.z, av.z, s); s = fmaf(wv.w, av.w, s);
        }
        wt[h * D_N + d] = s;
    }
}

// ---------------- K2: attn logits from fp16 xh ----------------
__global__ __launch_bounds__(256) void attn_kernel(
    const _Float16* __restrict__ xh, const float* __restrict__ wt,
    float* __restrict__ attn4)
{
    const int wid  = threadIdx.x >> 6;
    const int lane = threadIdx.x & 63;
    const int v    = blockIdx.x * 4 + wid;

    const f16x4 hv = *(const f16x4*)&xh[(size_t)v * D_N + lane * 4];
    const float p0 = (float)hv[0], p1 = (float)hv[1],
                p2 = (float)hv[2], p3 = (float)hv[3];

    float s[H_N];
    #pragma unroll
    for (int h = 0; h < H_N; ++h) {
        const float4 w = *(const float4*)&wt[h * D_N + lane * 4];
        float t = fmaf(p0, w.x, 0.f);
        t = fmaf(p1, w.y, t); t = fmaf(p2, w.z, t); t = fmaf(p3, w.w, t);
        s[h] = t;
    }
    #pragma unroll
    for (int h = 0; h < H_N; ++h)
        #pragma unroll
        for (int dd = 32; dd >= 1; dd >>= 1)
            s[h] += __shfl_xor(s[h], dd);
    if (lane == 0)
        *(float4*)&attn4[(size_t)v * 4] = make_float4(s[0], s[1], s[2], s[3]);
}

// ---------------- K3: fused softmax + row-gather + full-K fp16 MFMA ---------
__global__ __launch_bounds__(256, 4) void gat_kernel(
    const _Float16* __restrict__ xh, const float* __restrict__ attn4,
    const _Float16* __restrict__ Wt, const float* __restrict__ b,
    const int* __restrict__ adj, const int* __restrict__ mask_p,
    float* __restrict__ out)
{
    const int v0  = blockIdx.x * TM;
    const int tid = threadIdx.x;

    __shared__ int      sidx_s[TM][17];          // +1 pad
    __shared__ float    coefs_s[K_N][17][H_N];   // [k][node(+pad)][h]
    // yl slot (f16x8 units): h*512 + n*32 + (sl ^ n); sl = 32B slot of row
    __shared__ _Float16 yl[H_N * 512 * 8];       // 32KB

    // ---- P1: softmax coefs, thread = (node, k) ----
    {
        const int node = tid >> 4;
        const int k    = tid & 15;
        const int mask = mask_p[0];
        const int idx  = adj[(v0 + node) * K_N + k];
        const bool pad = (idx >= mask);
        const int safe = pad ? 0 : idx;
        const float4 av = *(const float4*)&attn4[(size_t)safe * 4];
        const float lg[H_N] = { pad ? NEG_INF : av.x, pad ? NEG_INF : av.y,
                                pad ? NEG_INF : av.z, pad ? NEG_INF : av.w };
        float c[H_N];
        #pragma unroll
        for (int h = 0; h < H_N; ++h) {
            float m = lg[h];
            #pragma unroll
            for (int s = 8; s >= 1; s >>= 1)
                m = fmaxf(m, __shfl_xor(m, s, 16));
            const float e = pad ? 0.f : __expf(lg[h] - m);
            float sum = e;
            #pragma unroll
            for (int s = 8; s >= 1; s >>= 1)
                sum += __shfl_xor(sum, s, 16);
            // pad coef 0 == ref (exp(-1e9-m)==0); all-pad row -> y=0 -> relu(bbar)
            c[h] = pad ? 0.f : e / sum;
        }
        *(float4*)&coefs_s[k][node][0] = make_float4(c[0], c[1], c[2], c[3]);
        sidx_s[node][k] = safe;
    }
    __syncthreads();

    const int wid  = tid >> 6;
    const int lane = tid & 63;
    // B-frag base for this wave's col tiles (used by prefetch + P3)
    const _Float16* Wb = Wt + (size_t)lane * 8 + (size_t)wid * 1024;

    // ---- P2: row-gather; wave owns nodes [wid*4, wid*4+4), contiguous rows ----
    // Packed fp16 accumulation: y[i][h] is f16x8, FMAs emit v_pk_fma_f16.
    {
        const int hw = lane >> 5;         // half-wave selects node parity
        const int sl = lane & 31;         // 16B slot within the 512B row
        const _Float16* xsl = xh + sl * 8;

        f16x8 y[2][H_N];                  // node = wid*4 + 2*i + hw
        #pragma unroll
        for (int i = 0; i < 2; ++i)
            #pragma unroll
            for (int h = 0; h < H_N; ++h)
                #pragma unroll
                for (int j = 0; j < 8; ++j) y[i][h][j] = (_Float16)0.f;

        #pragma unroll 4
        for (int k = 0; k < K_N; ++k) {
            #pragma unroll
            for (int i = 0; i < 2; ++i) {
                const int n  = wid * 4 + 2 * i + hw;
                const int si = sidx_s[n][k];
                const f16x8 xv = *(const f16x8*)&xsl[(size_t)si * D_N];
                const float4 c = *(const float4*)&coefs_s[k][n][0];
                const _Float16 c0 = (_Float16)c.x, c1 = (_Float16)c.y,
                               c2 = (_Float16)c.z, c3 = (_Float16)c.w;
                y[i][0] += xv * c0;
                y[i][1] += xv * c1;
                y[i][2] += xv * c2;
                y[i][3] += xv * c3;
            }
        }
        // store fp16 A-fragments, XOR-swizzled (write: contiguous permuted 512B)
        #pragma unroll
        for (int i = 0; i < 2; ++i) {
            const int n    = wid * 4 + 2 * i + hw;
            const int slot = n * 32 + (sl ^ n);
            #pragma unroll
            for (int h = 0; h < H_N; ++h)
                *(f16x8*)&yl[(size_t)(h * 512 + slot) * 8] = y[i][h];
        }
    }

    // Pre-barrier B-frag prefetch: issued now, completes during barrier drain.
    f16x8 cb0 = *(const f16x8*)&Wb[0];
    f16x8 cb1 = *(const f16x8*)&Wb[512];
    __syncthreads();

    // ---- P3: col tiles wid*2, wid*2+1; rotated pipeline over f = h*8+s ----
    const int m = lane & 15;              // node / C col
    const int q = lane >> 4;              // k-group / C row group
    f32x4 acc0 = (f32x4){0.f, 0.f, 0.f, 0.f};
    f32x4 acc1 = (f32x4){0.f, 0.f, 0.f, 0.f};
    #pragma unroll
    for (int f = 0; f < 32; ++f) {
        f16x8 nb0, nb1;
        if (f < 31) {
            nb0 = *(const f16x8*)&Wb[(size_t)(f + 1) * 4096];
            nb1 = *(const f16x8*)&Wb[(size_t)(f + 1) * 4096 + 512];
        }
        const int h    = f >> 3;
        const int s    = f & 7;
        const int slot = m * 32 + ((s * 4 + q) ^ m);
        const f16x8 af = *(const f16x8*)&yl[(size_t)(h * 512 + slot) * 8];
        acc0 = __builtin_amdgcn_mfma_f32_16x16x32_f16(af, cb0, acc0, 0, 0, 0);
        acc1 = __builtin_amdgcn_mfma_f32_16x16x32_f16(af, cb1, acc1, 0, 0, 0);
        cb0 = nb0; cb1 = nb1;
    }

    // ---- epilogue: mean heads + mean bias + relu; C: col=m, row=q*4+r ----
    #pragma unroll
    for (int nt = 0; nt < 2; ++nt) {
        const f32x4 acc = nt ? acc1 : acc0;
        const int col = (wid * 2 + nt) * 16 + m;
        const float bb = b[col] + b[O_N + col] + b[2 * O_N + col] + b[3 * O_N + col];
        #pragma unroll
        for (int r = 0; r < 4; ++r) {
            const int node = q * 4 + r;
            out[(size_t)(v0 + node) * O_N + col] = fmaxf(0.25f * (acc[r] + bb), 0.f);
        }
    }
}

extern "C" void kernel_launch(void* const* d_in, const int* in_sizes, int n_in,
                              void* d_out, int out_size, void* d_ws, size_t ws_size,
                              hipStream_t stream) {
    const float* x      = (const float*)d_in[0];
    const float* W      = (const float*)d_in[1];
    const float* a      = (const float*)d_in[2];
    const float* b      = (const float*)d_in[3];
    const int*   adj    = (const int*)d_in[4];
    const int*   mask_p = (const int*)d_in[5];
    float*       out    = (float*)d_out;

    // ws layout (bytes)
    char* p = (char*)d_ws;
    float*    attn4 = (float*)p;                     //    320,000
    _Float16* xh    = (_Float16*)(p + 320000);       // 10,240,000
    _Float16* Wt    = (_Float16*)(p + 10560000);     //    262,144
    float*    wt    = (float*)(p + 10822144);        //      4,096  (~10.8MB)

    prep_all_kernel<<<68 + V_N / 4, 256, 0, stream>>>(W, a, x, Wt, wt, xh);
    attn_kernel<<<V_N / 4, 256, 0, stream>>>(xh, wt, attn4);
    gat_kernel<<<V_N / TM, 256, 0, stream>>>(xh, attn4, Wt, b, adj, mask_p, out);
}